// Round 8
// baseline (129.260 us; speedup 1.0000x reference)
//
#include <hip/hip_runtime.h>

#define N_ATOMS 131072
#define N_TYPES 256
#define D 64
#define CAP 1024   // per-type capacity; counts ~Binomial(131072,1/256): mean 512, sd 22.6 -> 22 sigma
#define BPT 8      // blocks per type: 2048 blocks -> 8 blocks/CU -> 32 waves/CU (needs VGPR<=64)

using sfrag = __attribute__((ext_vector_type(8))) short;   // 8 bf16 (4 VGPRs)
using ffrag = __attribute__((ext_vector_type(4))) float;   // 4 fp32 acc

__device__ __forceinline__ short f2bf(float f)
{
    union { float f; unsigned u; } v; v.f = f;
    unsigned r = v.u + 0x7FFFu + ((v.u >> 16) & 1u);   // round-to-nearest-even
    return (short)(r >> 16);
}

__device__ __forceinline__ float fast_tanh(float v)
{
    float e = __expf(2.0f * v);
    return 1.0f - __fdividef(2.0f, e + 1.0f);
}

// ---------------------------------------------------------------------------
// Pass 1: counting sort (R6 version — measured fine). 128 blocks x 256 thr
// x 4 atoms; LDS-aggregated histogram -> one global atomic per nonzero bin.
// ---------------------------------------------------------------------------
__global__ __launch_bounds__(256) void scatter_kernel(
    const int* __restrict__ types, int* __restrict__ cursor, int* __restrict__ bucket)
{
    __shared__ int lhist[N_TYPES];
    __shared__ int lbase[N_TYPES];
    __shared__ int lcur[N_TYPES];
    const int tid  = threadIdx.x;
    const int base = blockIdx.x * 1024;
    lhist[tid] = 0;
    __syncthreads();

    int ty[4];
#pragma unroll
    for (int k = 0; k < 4; ++k) ty[k] = types[base + k * 256 + tid];   // coalesced
#pragma unroll
    for (int k = 0; k < 4; ++k) atomicAdd(&lhist[ty[k]], 1);
    __syncthreads();

    const int cnt = lhist[tid];
    if (cnt > 0) lbase[tid] = atomicAdd(&cursor[tid], cnt);
    lcur[tid] = 0;
    __syncthreads();

#pragma unroll
    for (int k = 0; k < 4; ++k) {
        const int t = ty[k];
        const int p = atomicAdd(&lcur[t], 1);
        const int q = lbase[t] + p;
        if (q < CAP) bucket[t * CAP + q] = base + k * 256 + tid;
    }
}

// ---------------------------------------------------------------------------
// Pass 2: MFMA bf16, zero LDS, ONE 16-atom group per wave (n<=512 typical).
// 2048 blocks -> 32 waves/CU; all waves' gathers overlap (TLP replaces the
// failed pipelining). Chain-breaking: bucket[g*16+c] is always in-bounds
// (CAP sizing), so it issues speculatively IN PARALLEL with cursor[t], the
// W-frags and bias; the VALUE is clamped ((unsigned)raw >= N_ATOMS -> 0,
// catches 0xAA ws-poison beyond n). Stores remain guarded by row < n.
// XCD affinity: b = t + 256*j -> all 8 blocks of type t on XCD t%8 -> W[t]
// L2-hit after the first block.
// ---------------------------------------------------------------------------
__global__ __launch_bounds__(256, 8) void apply_kernel(
    const float* __restrict__ x, const float* __restrict__ W,
    const float* __restrict__ b, const int* __restrict__ bucket,
    const int* __restrict__ cursor, float* __restrict__ out)
{
    const int t = blockIdx.x & 255;    // type: uniform across block
    const int j = blockIdx.x >> 8;     // 0..BPT-1

    const int wave = threadIdx.x >> 6;
    const int lane = threadIdx.x & 63;
    const int c = lane & 15;           // A: atom-in-tile | B/CD: output column
    const int q = lane >> 4;           // k-quad / CD row group

    const int*   bk = bucket + (size_t)t * CAP;
    const float* Wt = W + (size_t)t * (D * D);

    int g = j * 4 + wave;              // 0..31: one group per wave per trip

    // ---- speculative bucket read: always in-bounds, no dependence on n
    int raw = bk[g * 16 + c];

    // ---- n (scalar s_load; runs in parallel with everything below)
    int n = cursor[t];
    if (n > CAP) n = CAP;

    // ---- B-frags: B[k][nn] = W[nn][k]; lane holds W[nt*16+c][ks*32+q*8+jj]
    sfrag Bf[4][2];
#pragma unroll
    for (int nt = 0; nt < 4; ++nt) {
#pragma unroll
        for (int ks = 0; ks < 2; ++ks) {
            const float4* wr = (const float4*)(Wt + (size_t)(nt * 16 + c) * D + ks * 32 + q * 8);
            float4 w0 = wr[0], w1 = wr[1];
            sfrag f;
            f[0] = f2bf(w0.x); f[1] = f2bf(w0.y); f[2] = f2bf(w0.z); f[3] = f2bf(w0.w);
            f[4] = f2bf(w1.x); f[5] = f2bf(w1.y); f[6] = f2bf(w1.z); f[7] = f2bf(w1.w);
            Bf[nt][ks] = f;
        }
    }
    float bias[4];
#pragma unroll
    for (int nt = 0; nt < 4; ++nt) bias[nt] = b[(size_t)t * D + nt * 16 + c];

    if (g * 16 >= n) return;           // outstanding loads discarded at endpgm

    while (true) {
        // clamp VALUE (poison/garbage -> row 0; stores still guarded by n)
        int aidx = ((unsigned)raw >= (unsigned)N_ATOMS) ? 0 : raw;

        // ---- x gather: 4 dwordx4 per lane (rows random; lanes 0..15 = rows)
        const float4* xr = (const float4*)x + (size_t)aidx * 16 + q * 2;
        float4 x0 = xr[0], x1 = xr[1], x2 = xr[8], x3 = xr[9];

        sfrag A0, A1;
        A0[0] = f2bf(x0.x); A0[1] = f2bf(x0.y); A0[2] = f2bf(x0.z); A0[3] = f2bf(x0.w);
        A0[4] = f2bf(x1.x); A0[5] = f2bf(x1.y); A0[6] = f2bf(x1.z); A0[7] = f2bf(x1.w);
        A1[0] = f2bf(x2.x); A1[1] = f2bf(x2.y); A1[2] = f2bf(x2.z); A1[3] = f2bf(x2.w);
        A1[4] = f2bf(x3.x); A1[5] = f2bf(x3.y); A1[6] = f2bf(x3.z); A1[7] = f2bf(x3.w);

        const int base = g * 16;
        int  oat[4]; bool ov[4];
#pragma unroll
        for (int r = 0; r < 4; ++r) {
            ov[r]  = (base + q * 4 + r) < n;
            oat[r] = __shfl(aidx, q * 4 + r, 64);   // lanes 0..15 hold bucket[base+0..15]
        }

#pragma unroll
        for (int nt = 0; nt < 4; ++nt) {
            ffrag acc = {0.f, 0.f, 0.f, 0.f};
            acc = __builtin_amdgcn_mfma_f32_16x16x32_bf16(A0, Bf[nt][0], acc, 0, 0, 0);
            acc = __builtin_amdgcn_mfma_f32_16x16x32_bf16(A1, Bf[nt][1], acc, 0, 0, 0);
#pragma unroll
            for (int r = 0; r < 4; ++r) {
                if (ov[r])
                    out[(size_t)oat[r] * D + nt * 16 + c] = fast_tanh(acc[r] + bias[nt]);
            }
        }

        g += 4 * BPT;                  // 32 waves per type: rare 2nd trip (n>512)
        if (g * 16 >= n) break;
        raw = bk[g * 16 + c];          // still always in-bounds (g*16+c < CAP)
    }
}

extern "C" void kernel_launch(void* const* d_in, const int* in_sizes, int n_in,
                              void* d_out, int out_size, void* d_ws, size_t ws_size,
                              hipStream_t stream)
{
    const float* x     = (const float*)d_in[0];
    const int*   types = (const int*)  d_in[1];
    const float* W     = (const float*)d_in[2];
    const float* b     = (const float*)d_in[3];
    float*       out   = (float*)d_out;

    int* cursor = (int*)d_ws;
    int* bucket = (int*)((char*)d_ws + 1024);

    hipMemsetAsync(cursor, 0, N_TYPES * sizeof(int), stream);
    scatter_kernel<<<dim3(N_ATOMS / 1024), dim3(256), 0, stream>>>(types, cursor, bucket);
    apply_kernel<<<dim3(BPT * N_TYPES), dim3(256), 0, stream>>>(x, W, b, bucket, cursor, out);
}

// Round 9
// 107.917 us; speedup vs baseline: 1.1978x; 1.1978x over previous
//
#include <hip/hip_runtime.h>

#define N_ATOMS 131072
#define N_TYPES 256
#define D 64
#define CAP 1024   // per-type capacity; counts ~Binomial(131072,1/256): mean 512, sd 22.6 -> 22 sigma
#define BPT 4      // blocks per type: 1024 blocks, 128-VGPR budget, 16 waves/CU (TLP ceiling per R8)

using sfrag = __attribute__((ext_vector_type(8))) short;   // 8 bf16 (4 VGPRs)
using ffrag = __attribute__((ext_vector_type(4))) float;   // 4 fp32 acc

__device__ __forceinline__ short f2bf(float f)
{
    union { float f; unsigned u; } v; v.f = f;
    unsigned r = v.u + 0x7FFFu + ((v.u >> 16) & 1u);   // round-to-nearest-even
    return (short)(r >> 16);
}

__device__ __forceinline__ float fast_tanh(float v)
{
    float e = __expf(2.0f * v);
    return 1.0f - __fdividef(2.0f, e + 1.0f);
}

// ---------------------------------------------------------------------------
// Pass 1: counting sort (R6-proven). 128 blocks x 256 thr x 4 atoms;
// LDS-aggregated histogram -> one global atomic per nonzero bin.
// ---------------------------------------------------------------------------
__global__ __launch_bounds__(256) void scatter_kernel(
    const int* __restrict__ types, int* __restrict__ cursor, int* __restrict__ bucket)
{
    __shared__ int lhist[N_TYPES];
    __shared__ int lbase[N_TYPES];
    __shared__ int lcur[N_TYPES];
    const int tid  = threadIdx.x;
    const int base = blockIdx.x * 1024;
    lhist[tid] = 0;
    __syncthreads();

    int ty[4];
#pragma unroll
    for (int k = 0; k < 4; ++k) ty[k] = types[base + k * 256 + tid];   // coalesced
#pragma unroll
    for (int k = 0; k < 4; ++k) atomicAdd(&lhist[ty[k]], 1);
    __syncthreads();

    const int cnt = lhist[tid];
    if (cnt > 0) lbase[tid] = atomicAdd(&cursor[tid], cnt);
    lcur[tid] = 0;
    __syncthreads();

#pragma unroll
    for (int k = 0; k < 4; ++k) {
        const int t = ty[k];
        const int p = atomicAdd(&lcur[t], 1);
        const int q = lbase[t] + p;
        if (q < CAP) bucket[t * CAP + q] = base + k * 256 + tid;
    }
}

// ---------------------------------------------------------------------------
// Pass 2: MFMA bf16, zero LDS, TWO groups per wave processed WIDE (not
// pipelined): both bucket reads issue speculatively (always in-bounds by CAP
// sizing, value-clamped against ws-poison), both x gathers in flight
// together (8 dwordx4 outstanding vs 4) -> 2x MLP in the latency-bound
// regime (R8 showed 3.5 TB/s effective on random 256B granules; TLP is
// capped at 16 waves/CU by the 128-VGPR occupancy step, so MLP is the only
// lever left). XCD affinity: b = t + 256*j -> type t's blocks on XCD t%8.
// ---------------------------------------------------------------------------
__global__ __launch_bounds__(256, 4) void apply_kernel(
    const float* __restrict__ x, const float* __restrict__ W,
    const float* __restrict__ b, const int* __restrict__ bucket,
    const int* __restrict__ cursor, float* __restrict__ out)
{
    const int t = blockIdx.x & 255;    // type: uniform across block
    const int j = blockIdx.x >> 8;     // 0..BPT-1

    const int wave = threadIdx.x >> 6;
    const int lane = threadIdx.x & 63;
    const int c = lane & 15;           // A: atom-in-tile | B/CD: output column
    const int q = lane >> 4;           // k-quad / CD row group

    const int*   bk = bucket + (size_t)t * CAP;
    const float* Wt = W + (size_t)t * (D * D);

    int p = j * 4 + wave;              // pair index: groups 2p, 2p+1

    // ---- speculative bucket reads for BOTH groups (heads of the chain)
    int raw0 = bk[(2 * p + 0) * 16 + c];       // max index 62*16+15 < CAP
    int raw1 = bk[(2 * p + 1) * 16 + c];       // max index 63*16+15 < CAP

    // ---- n (scalar load; overlaps everything)
    int n = cursor[t];
    if (n > CAP) n = CAP;

    // ---- B-frags: B[k][nn] = W[nn][k]; lane holds W[nt*16+c][ks*32+q*8+jj]
    sfrag Bf[4][2];
#pragma unroll
    for (int nt = 0; nt < 4; ++nt) {
#pragma unroll
        for (int ks = 0; ks < 2; ++ks) {
            const float4* wr = (const float4*)(Wt + (size_t)(nt * 16 + c) * D + ks * 32 + q * 8);
            float4 w0 = wr[0], w1 = wr[1];
            sfrag f;
            f[0] = f2bf(w0.x); f[1] = f2bf(w0.y); f[2] = f2bf(w0.z); f[3] = f2bf(w0.w);
            f[4] = f2bf(w1.x); f[5] = f2bf(w1.y); f[6] = f2bf(w1.z); f[7] = f2bf(w1.w);
            Bf[nt][ks] = f;
        }
    }
    float bias[4];
#pragma unroll
    for (int nt = 0; nt < 4; ++nt) bias[nt] = b[(size_t)t * D + nt * 16 + c];

    if (2 * p * 16 >= n) return;       // outstanding loads discarded at endpgm

    while (true) {
        const int g0 = 2 * p, g1 = 2 * p + 1;
        const bool do1 = (g1 * 16 < n);          // wave-uniform

        // clamp VALUES (0xAA poison / garbage beyond n -> row 0; stores guarded)
        const int ia = ((unsigned)raw0 >= (unsigned)N_ATOMS) ? 0 : raw0;
        const int ib = ((unsigned)raw1 >= (unsigned)N_ATOMS) ? 0 : raw1;

        // ---- BOTH x gathers in flight together (8 dwordx4 outstanding)
        const float4* xra = (const float4*)x + (size_t)ia * 16 + q * 2;
        const float4* xrb = (const float4*)x + (size_t)ib * 16 + q * 2;
        float4 a0 = xra[0], a1 = xra[1], a2 = xra[8], a3 = xra[9];
        float4 b0 = xrb[0], b1 = xrb[1], b2 = xrb[8], b3 = xrb[9];

        // ---- group 0 compute
        {
            sfrag A0, A1;
            A0[0] = f2bf(a0.x); A0[1] = f2bf(a0.y); A0[2] = f2bf(a0.z); A0[3] = f2bf(a0.w);
            A0[4] = f2bf(a1.x); A0[5] = f2bf(a1.y); A0[6] = f2bf(a1.z); A0[7] = f2bf(a1.w);
            A1[0] = f2bf(a2.x); A1[1] = f2bf(a2.y); A1[2] = f2bf(a2.z); A1[3] = f2bf(a2.w);
            A1[4] = f2bf(a3.x); A1[5] = f2bf(a3.y); A1[6] = f2bf(a3.z); A1[7] = f2bf(a3.w);

            const int base = g0 * 16;
            int  oat[4]; bool ov[4];
#pragma unroll
            for (int r = 0; r < 4; ++r) {
                ov[r]  = (base + q * 4 + r) < n;
                oat[r] = __shfl(ia, q * 4 + r, 64);   // lanes 0..15 hold rows base+0..15
            }
#pragma unroll
            for (int nt = 0; nt < 4; ++nt) {
                ffrag acc = {0.f, 0.f, 0.f, 0.f};
                acc = __builtin_amdgcn_mfma_f32_16x16x32_bf16(A0, Bf[nt][0], acc, 0, 0, 0);
                acc = __builtin_amdgcn_mfma_f32_16x16x32_bf16(A1, Bf[nt][1], acc, 0, 0, 0);
#pragma unroll
                for (int r = 0; r < 4; ++r) {
                    if (ov[r])
                        out[(size_t)oat[r] * D + nt * 16 + c] = fast_tanh(acc[r] + bias[nt]);
                }
            }
        }

        // ---- group 1 compute (wave-uniform skip)
        if (do1) {
            sfrag A0, A1;
            A0[0] = f2bf(b0.x); A0[1] = f2bf(b0.y); A0[2] = f2bf(b0.z); A0[3] = f2bf(b0.w);
            A0[4] = f2bf(b1.x); A0[5] = f2bf(b1.y); A0[6] = f2bf(b1.z); A0[7] = f2bf(b1.w);
            A1[0] = f2bf(b2.x); A1[1] = f2bf(b2.y); A1[2] = f2bf(b2.z); A1[3] = f2bf(b2.w);
            A1[4] = f2bf(b3.x); A1[5] = f2bf(b3.y); A1[6] = f2bf(b3.z); A1[7] = f2bf(b3.w);

            const int base = g1 * 16;
            int  oat[4]; bool ov[4];
#pragma unroll
            for (int r = 0; r < 4; ++r) {
                ov[r]  = (base + q * 4 + r) < n;
                oat[r] = __shfl(ib, q * 4 + r, 64);
            }
#pragma unroll
            for (int nt = 0; nt < 4; ++nt) {
                ffrag acc = {0.f, 0.f, 0.f, 0.f};
                acc = __builtin_amdgcn_mfma_f32_16x16x32_bf16(A0, Bf[nt][0], acc, 0, 0, 0);
                acc = __builtin_amdgcn_mfma_f32_16x16x32_bf16(A1, Bf[nt][1], acc, 0, 0, 0);
#pragma unroll
                for (int r = 0; r < 4; ++r) {
                    if (ov[r])
                        out[(size_t)oat[r] * D + nt * 16 + c] = fast_tanh(acc[r] + bias[nt]);
                }
            }
        }

        p += 4 * BPT;                  // 16 pairs = 32 groups per trip; n>512 -> 2nd trip
        if (2 * p * 16 >= n) break;
        raw0 = bk[(2 * p + 0) * 16 + c];
        raw1 = bk[(2 * p + 1) * 16 + c];
    }
}

extern "C" void kernel_launch(void* const* d_in, const int* in_sizes, int n_in,
                              void* d_out, int out_size, void* d_ws, size_t ws_size,
                              hipStream_t stream)
{
    const float* x     = (const float*)d_in[0];
    const int*   types = (const int*)  d_in[1];
    const float* W     = (const float*)d_in[2];
    const float* b     = (const float*)d_in[3];
    float*       out   = (float*)d_out;

    int* cursor = (int*)d_ws;
    int* bucket = (int*)((char*)d_ws + 1024);

    hipMemsetAsync(cursor, 0, N_TYPES * sizeof(int), stream);
    scatter_kernel<<<dim3(N_ATOMS / 1024), dim3(256), 0, stream>>>(types, cursor, bucket);
    apply_kernel<<<dim3(BPT * N_TYPES), dim3(256), 0, stream>>>(x, W, b, bucket, cursor, out);
}